// Round 3
// baseline (162.104 us; speedup 1.0000x reference)
//
#include <hip/hip_runtime.h>
#include <hip/hip_bf16.h>

// LengthRegulator: x[B,T,D] f32, duration[B,T] i32, src_lens[B] i32, max_len=4096.
// out = gather-expand rows of x per cumulative duration; frames >= tgt_len are 0.
// d_out layout (all float32): out[B*L*D] then tgt_len[B] (as float).

#define BB 32
#define TT 512
#define DD 256
#define LL 4096
#define D4 (DD / 4)   // 64 float4 per row
#define FPB 64        // frames per block
#define BPB (LL / FPB) // blocks per batch = 64

__global__ __launch_bounds__(256) void length_regulator_kernel(
    const float4* __restrict__ x,
    const int*    __restrict__ duration,
    const int*    __restrict__ src_lens,
    float*        __restrict__ out_f)
{
    __shared__ int sc[2][TT];

    const int b     = blockIdx.x / BPB;
    const int chunk = blockIdx.x % BPB;
    const int tid   = threadIdx.x;

    const int slen = src_lens[b];

    // Load masked durations into LDS.
    for (int i = tid; i < TT; i += 256) {
        int d = duration[b * TT + i];
        sc[0][i] = (i < slen) ? d : 0;
    }
    __syncthreads();

    // Inclusive scan (Hillis-Steele, double-buffered), 512 elems, 9 steps.
    int src = 0;
    for (int off = 1; off < TT; off <<= 1) {
        for (int i = tid; i < TT; i += 256) {
            int v = sc[src][i];
            if (i >= off) v += sc[src][i - off];
            sc[src ^ 1][i] = v;
        }
        __syncthreads();
        src ^= 1;
    }
    const int* cum = sc[src];
    const int tlen = cum[TT - 1];

    // One block per batch writes tgt_len (as float) at the tail of d_out.
    if (chunk == 0 && tid == 0) {
        out_f[(size_t)BB * LL * DD + b] = (float)tlen;
    }

    float4* out4 = (float4*)out_f;
    const int wave = tid >> 6;
    const int lane = tid & 63;

    // 4 waves per block; each wave copies one full 1KB row per iteration
    // (64 lanes x float4, perfectly coalesced).
    for (int f = wave; f < FPB; f += 4) {
        const int j = chunk * FPB + f;
        float4 v;
        if (j >= tlen) {
            v = make_float4(0.f, 0.f, 0.f, 0.f);
        } else {
            // searchsorted right: first idx with cum[idx] > j
            int lo = 0, hi = TT;
            while (lo < hi) {
                int mid = (lo + hi) >> 1;
                if (cum[mid] > j) hi = mid; else lo = mid + 1;
            }
            int idx = lo < (TT - 1) ? lo : (TT - 1);
            v = x[((size_t)b * TT + idx) * D4 + lane];
        }
        out4[((size_t)b * LL + j) * D4 + lane] = v;
    }
}

extern "C" void kernel_launch(void* const* d_in, const int* in_sizes, int n_in,
                              void* d_out, int out_size, void* d_ws, size_t ws_size,
                              hipStream_t stream) {
    const float4* x        = (const float4*)d_in[0];
    const int*    duration = (const int*)d_in[1];
    const int*    src_lens = (const int*)d_in[2];
    float*        out_f    = (float*)d_out;

    dim3 grid(BB * BPB);  // 2048 blocks
    dim3 block(256);
    length_regulator_kernel<<<grid, block, 0, stream>>>(x, duration, src_lens, out_f);
}